// Round 1
// baseline (3717.286 us; speedup 1.0000x reference)
//
#include <hip/hip_runtime.h>
#include <math.h>

#define NHEADS 8
#define NDIM 8
#define F_IN 14
#define NSLOPE 0.2f

__device__ __forceinline__ float leaky(float v) { return v >= 0.f ? v : NSLOPE * v; }

// K1: per-node layer-1: h1 = x@W1, attention alphas, self-loop init of num1/den1
__global__ void k1_node_l1(const float* __restrict__ x,
                           const float* __restrict__ W1,
                           const float* __restrict__ a_src,
                           const float* __restrict__ a_dst,
                           float* __restrict__ h1,
                           float* __restrict__ num1,
                           float* __restrict__ as1,
                           float* __restrict__ ad1,
                           float* __restrict__ den1,
                           int N)
{
    __shared__ float W[F_IN * 64];
    int t = threadIdx.x;
    for (int idx = t; idx < F_IN * 64; idx += 256) W[idx] = W1[idx];
    __syncthreads();
    int node = blockIdx.x * 4 + (t >> 6);
    int f = t & 63;
    if (node >= N) return;
    const float* xr = x + (size_t)node * F_IN;
    float h = 0.f;
#pragma unroll
    for (int k = 0; k < F_IN; ++k) h += xr[k] * W[k * 64 + f];
    int head = f >> 3, d = f & 7;
    float vs = h * a_src[head * 8 + d];
    float vd = h * a_dst[head * 8 + d];
    vs += __shfl_xor(vs, 1, 8); vs += __shfl_xor(vs, 2, 8); vs += __shfl_xor(vs, 4, 8);
    vd += __shfl_xor(vd, 1, 8); vd += __shfl_xor(vd, 2, 8); vd += __shfl_xor(vd, 4, 8);
    float ex = __expf(leaky(vs + vd));   // self-loop edge (i->i): as[i]+ad[i]
    if (d == 0) {
        as1[node * 8 + head] = vs;
        ad1[node * 8 + head] = vd;
        den1[node * 8 + head] = ex;
    }
    h1[(size_t)node * 64 + f] = h;
    num1[(size_t)node * 64 + f] = ex * h;
}

// K2: per (edge, head) scatter: num1[i] += ex*h1[j], den1[i] += ex
__global__ void k2_edge_l1(const int* __restrict__ ei, int E,
                           const float* __restrict__ h1,
                           const float* __restrict__ as1,
                           const float* __restrict__ ad1,
                           float* __restrict__ num1,
                           float* __restrict__ den1)
{
    long long gid = (long long)blockIdx.x * blockDim.x + threadIdx.x;
    if (gid >= (long long)E * 8) return;
    int edge = (int)(gid >> 3), head = (int)(gid & 7);
    int j = ei[edge];        // src
    int i = ei[E + edge];    // dst
    float ex = __expf(leaky(as1[j * 8 + head] + ad1[i * 8 + head]));
    atomicAdd(&den1[i * 8 + head], ex);
    const float* hs = h1 + (size_t)j * 64 + head * 8;
    float* np_ = num1 + (size_t)i * 64 + head * 8;
#pragma unroll
    for (int d = 0; d < 8; ++d) atomicAdd(&np_[d], ex * hs[d]);
}

// K3a: finish layer 1: hl2 = elu(num1/den1 + bias1)   (hl2 aliases h1 buffer)
__global__ void k3a_finish_l1(const float* __restrict__ num1,
                              const float* __restrict__ den1,
                              const float* __restrict__ bias1,
                              float* __restrict__ hl2, int N)
{
    int tid = blockIdx.x * blockDim.x + threadIdx.x;
    if (tid >= N * 64) return;
    int node = tid >> 6;
    int head = (tid >> 3) & 7;
    float v = num1[tid] / (den1[node * 8 + head] + 1e-16f) + bias1[tid & 63];
    hl2[tid] = v > 0.f ? v : (__expf(v) - 1.f);
}

// K3b: per-node layer-2: h2 = hl2@W2, alphas, self-loop init of num2/den2
__global__ void k3b_node_l2(const float* __restrict__ hl2,
                            const float* __restrict__ W2,
                            const float* __restrict__ a_src2,
                            const float* __restrict__ a_dst2,
                            float* __restrict__ h2,
                            float* __restrict__ num2,
                            float* __restrict__ as2,
                            float* __restrict__ ad2,
                            float* __restrict__ den2, int N)
{
    __shared__ float W[64 * 8];
    int t = threadIdx.x;
    for (int idx = t; idx < 512; idx += 256) W[idx] = W2[idx];
    __syncthreads();
    int node = blockIdx.x * 32 + (t >> 3);
    int d = t & 7;
    if (node >= N) return;
    const float* hr = hl2 + (size_t)node * 64;
    float acc = 0.f;
#pragma unroll
    for (int f = 0; f < 64; ++f) acc += hr[f] * W[f * 8 + d];
    float vs = acc * a_src2[d];
    float vd = acc * a_dst2[d];
    vs += __shfl_xor(vs, 1, 8); vs += __shfl_xor(vs, 2, 8); vs += __shfl_xor(vs, 4, 8);
    vd += __shfl_xor(vd, 1, 8); vd += __shfl_xor(vd, 2, 8); vd += __shfl_xor(vd, 4, 8);
    float ex = __expf(leaky(vs + vd));
    if (d == 0) {
        as2[node] = vs;
        ad2[node] = vd;
        den2[node] = ex;
    }
    h2[node * 8 + d] = acc;
    num2[node * 8 + d] = ex * acc;
}

// K4: per-edge layer-2 scatter
__global__ void k4_edge_l2(const int* __restrict__ ei, int E,
                           const float* __restrict__ h2,
                           const float* __restrict__ as2,
                           const float* __restrict__ ad2,
                           float* __restrict__ num2,
                           float* __restrict__ den2)
{
    int e = blockIdx.x * blockDim.x + threadIdx.x;
    if (e >= E) return;
    int j = ei[e];
    int i = ei[E + e];
    float ex = __expf(leaky(as2[j] + ad2[i]));
    atomicAdd(&den2[i], ex);
    const float* hs = h2 + (size_t)j * 8;
    float* np_ = num2 + (size_t)i * 8;
#pragma unroll
    for (int d = 0; d < 8; ++d) atomicAdd(&np_[d], ex * hs[d]);
}

// K5: out = num2/den2 + bias2
__global__ void k5_out(const float* __restrict__ num2,
                       const float* __restrict__ den2,
                       const float* __restrict__ bias2,
                       float* __restrict__ out, int N)
{
    int tid = blockIdx.x * blockDim.x + threadIdx.x;
    if (tid >= N * 8) return;
    out[tid] = num2[tid] / (den2[tid >> 3] + 1e-16f) + bias2[tid & 7];
}

extern "C" void kernel_launch(void* const* d_in, const int* in_sizes, int n_in,
                              void* d_out, int out_size, void* d_ws, size_t ws_size,
                              hipStream_t stream) {
    const float* x    = (const float*)d_in[0];
    const int*   ei   = (const int*)d_in[1];
    const float* W1   = (const float*)d_in[2];
    const float* asw1 = (const float*)d_in[3];
    const float* adw1 = (const float*)d_in[4];
    const float* b1   = (const float*)d_in[5];
    const float* W2   = (const float*)d_in[6];
    const float* asw2 = (const float*)d_in[7];
    const float* adw2 = (const float*)d_in[8];
    const float* b2   = (const float*)d_in[9];
    float* out = (float*)d_out;

    int N = in_sizes[0] / F_IN;
    int E = in_sizes[1] / 2;

    float* ws   = (float*)d_ws;
    float* h1   = ws;                        // N*64  (reused as hl2 after K3a)
    float* num1 = h1   + (size_t)N * 64;     // N*64
    float* as1  = num1 + (size_t)N * 64;     // N*8
    float* ad1  = as1  + (size_t)N * 8;      // N*8
    float* den1 = ad1  + (size_t)N * 8;      // N*8
    float* h2   = den1 + (size_t)N * 8;      // N*8
    float* num2 = h2   + (size_t)N * 8;      // N*8
    float* as2  = num2 + (size_t)N * 8;      // N
    float* ad2  = as2  + (size_t)N;          // N
    float* den2 = ad2  + (size_t)N;          // N

    k1_node_l1<<<(N + 3) / 4, 256, 0, stream>>>(x, W1, asw1, adw1, h1, num1, as1, ad1, den1, N);

    long long tot1 = (long long)E * 8;
    k2_edge_l1<<<(int)((tot1 + 255) / 256), 256, 0, stream>>>(ei, E, h1, as1, ad1, num1, den1);

    k3a_finish_l1<<<(N * 64 + 255) / 256, 256, 0, stream>>>(num1, den1, b1, h1, N);

    k3b_node_l2<<<(N + 31) / 32, 256, 0, stream>>>(h1, W2, asw2, adw2, h2, num2, as2, ad2, den2, N);

    k4_edge_l2<<<(E + 255) / 256, 256, 0, stream>>>(ei, E, h2, as2, ad2, num2, den2);

    k5_out<<<(N * 8 + 255) / 256, 256, 0, stream>>>(num2, den2, b2, out, N);
}

// Round 2
// 365.297 us; speedup vs baseline: 10.1761x; 10.1761x over previous
//
#include <hip/hip_runtime.h>
#include <math.h>

#define F_IN 14
#define NSLOPE 0.2f

__device__ __forceinline__ float leaky(float v) { return v >= 0.f ? v : NSLOPE * v; }

// ---------- CSR build ----------

__global__ void zero_int(int* p, int n) {
    for (int i = blockIdx.x * blockDim.x + threadIdx.x; i < n; i += gridDim.x * blockDim.x)
        p[i] = 0;
}

__global__ void count_deg(const int* __restrict__ ei, int E, int* __restrict__ deg) {
    int e = blockIdx.x * blockDim.x + threadIdx.x;
    if (e >= E) return;
    atomicAdd(&deg[ei[E + e]], 1);   // dst
}

// block-level scan: 256 threads x 4 elems = 1024 elems/block
__global__ void scan1(const int* __restrict__ deg, int* __restrict__ partial,
                      int* __restrict__ blocksum, int N) {
    __shared__ int s[256];
    int b = blockIdx.x, t = threadIdx.x;
    int base = b * 1024 + t * 4;
    int v[4], sum = 0;
#pragma unroll
    for (int u = 0; u < 4; ++u) {
        int idx = base + u;
        int x = (idx < N) ? deg[idx] : 0;
        v[u] = sum; sum += x;
    }
    s[t] = sum;
    __syncthreads();
    for (int off = 1; off < 256; off <<= 1) {
        int x = (t >= off) ? s[t - off] : 0;
        __syncthreads();
        s[t] += x;
        __syncthreads();
    }
    int excl = (t == 0) ? 0 : s[t - 1];
    if (t == 255) blocksum[b] = s[255];
#pragma unroll
    for (int u = 0; u < 4; ++u) {
        int idx = base + u;
        if (idx < N) partial[idx] = excl + v[u];
    }
}

// single-block exclusive scan of block sums (supports any nblk via chunked loop)
__global__ void scan2(int* __restrict__ blocksum, int nblk) {
    __shared__ int s[256];
    __shared__ int carry_s;
    int t = threadIdx.x;
    if (t == 0) carry_s = 0;
    __syncthreads();
    for (int start = 0; start < nblk; start += 256) {
        int idx = start + t;
        int x = (idx < nblk) ? blocksum[idx] : 0;
        s[t] = x;
        __syncthreads();
        for (int off = 1; off < 256; off <<= 1) {
            int y = (t >= off) ? s[t - off] : 0;
            __syncthreads();
            s[t] += y;
            __syncthreads();
        }
        int carry = carry_s;
        if (idx < nblk) blocksum[idx] = carry + s[t] - x;   // exclusive
        __syncthreads();
        if (t == 255) carry_s = carry + s[255];
        __syncthreads();
    }
}

__global__ void scan3(const int* __restrict__ partial, const int* __restrict__ blocksum,
                      int* __restrict__ rowstart, int* __restrict__ cursor, int N) {
    int i = blockIdx.x * blockDim.x + threadIdx.x;
    if (i >= N) return;
    int r = partial[i] + blocksum[i >> 10];
    rowstart[i] = r;
    cursor[i] = r;
}

__global__ void scatter_csr(const int* __restrict__ ei, int E,
                            int* __restrict__ cursor, int* __restrict__ csr) {
    int e = blockIdx.x * blockDim.x + threadIdx.x;
    if (e >= E) return;
    int j = ei[e];          // src
    int i = ei[E + e];      // dst
    int pos = atomicAdd(&cursor[i], 1);
    csr[pos] = j;
}

// ---------- Layer 1 ----------

// per-node: h1 = x@W1 [N,64], per-head alpha_src/alpha_dst [N,8]
__global__ void k1_node_l1(const float* __restrict__ x,
                           const float* __restrict__ W1,
                           const float* __restrict__ a_src,
                           const float* __restrict__ a_dst,
                           float* __restrict__ h1,
                           float* __restrict__ as1,
                           float* __restrict__ ad1,
                           int N)
{
    __shared__ float W[F_IN * 64];
    int t = threadIdx.x;
    for (int idx = t; idx < F_IN * 64; idx += 256) W[idx] = W1[idx];
    __syncthreads();
    int node = blockIdx.x * 4 + (t >> 6);
    int f = t & 63;
    if (node >= N) return;
    const float* xr = x + (size_t)node * F_IN;
    float h = 0.f;
#pragma unroll
    for (int k = 0; k < F_IN; ++k) h += xr[k] * W[k * 64 + f];
    int head = f >> 3, d = f & 7;
    float vs = h * a_src[head * 8 + d];
    float vd = h * a_dst[head * 8 + d];
    vs += __shfl_xor(vs, 1, 8); vs += __shfl_xor(vs, 2, 8); vs += __shfl_xor(vs, 4, 8);
    vd += __shfl_xor(vd, 1, 8); vd += __shfl_xor(vd, 2, 8); vd += __shfl_xor(vd, 4, 8);
    if (d == 0) {
        as1[node * 8 + head] = vs;
        ad1[node * 8 + head] = vd;
    }
    h1[(size_t)node * 64 + f] = h;
}

// gather: thread = (node, head); accumulate softmax num/den over incoming edges
// (incl. self-loop), then fused  hl2 = elu(num/den + bias1)
__global__ void k2_gather_l1(const int* __restrict__ rowstart,
                             const int* __restrict__ deg,
                             const int* __restrict__ csr,
                             const float* __restrict__ h1,
                             const float* __restrict__ as1,
                             const float* __restrict__ ad1,
                             const float* __restrict__ bias1,
                             float* __restrict__ hl2, int N)
{
    int t = threadIdx.x;
    int node = blockIdx.x * 32 + (t >> 3);
    int head = t & 7;
    if (node >= N) return;
    float adi = ad1[node * 8 + head];
    float asi = as1[node * 8 + head];
    float ex = __expf(leaky(asi + adi));          // self-loop
    float den = ex;
    const float4* hp = (const float4*)(h1 + (size_t)node * 64 + head * 8);
    float4 a0 = hp[0], a1 = hp[1];
    float n0 = ex * a0.x, n1 = ex * a0.y, n2 = ex * a0.z, n3 = ex * a0.w;
    float n4 = ex * a1.x, n5 = ex * a1.y, n6 = ex * a1.z, n7 = ex * a1.w;
    int base = rowstart[node], cnt = deg[node];
    for (int k = 0; k < cnt; ++k) {
        int j = csr[base + k];
        float e2 = __expf(leaky(as1[j * 8 + head] + adi));
        const float4* hj = (const float4*)(h1 + (size_t)j * 64 + head * 8);
        float4 x0 = hj[0], x1 = hj[1];
        den += e2;
        n0 += e2 * x0.x; n1 += e2 * x0.y; n2 += e2 * x0.z; n3 += e2 * x0.w;
        n4 += e2 * x1.x; n5 += e2 * x1.y; n6 += e2 * x1.z; n7 += e2 * x1.w;
    }
    float inv = 1.f / (den + 1e-16f);
    const float* bp = bias1 + head * 8;
    float o[8] = { n0, n1, n2, n3, n4, n5, n6, n7 };
    float* op = hl2 + (size_t)node * 64 + head * 8;
#pragma unroll
    for (int u = 0; u < 8; ++u) {
        float v = o[u] * inv + bp[u];
        op[u] = v > 0.f ? v : (__expf(v) - 1.f);
    }
}

// ---------- Layer 2 ----------

__global__ void k3_node_l2(const float* __restrict__ hl2,
                           const float* __restrict__ W2,
                           const float* __restrict__ a_src2,
                           const float* __restrict__ a_dst2,
                           float* __restrict__ h2,
                           float* __restrict__ as2,
                           float* __restrict__ ad2, int N)
{
    __shared__ float W[64 * 8];
    int t = threadIdx.x;
    for (int idx = t; idx < 512; idx += 256) W[idx] = W2[idx];
    __syncthreads();
    int node = blockIdx.x * 32 + (t >> 3);
    int d = t & 7;
    if (node >= N) return;
    const float* hr = hl2 + (size_t)node * 64;
    float acc = 0.f;
#pragma unroll
    for (int f = 0; f < 64; ++f) acc += hr[f] * W[f * 8 + d];
    float vs = acc * a_src2[d];
    float vd = acc * a_dst2[d];
    vs += __shfl_xor(vs, 1, 8); vs += __shfl_xor(vs, 2, 8); vs += __shfl_xor(vs, 4, 8);
    vd += __shfl_xor(vd, 1, 8); vd += __shfl_xor(vd, 2, 8); vd += __shfl_xor(vd, 4, 8);
    if (d == 0) {
        as2[node] = vs;
        ad2[node] = vd;
    }
    h2[node * 8 + d] = acc;
}

// gather: thread = (node, d); fused  out = num/den + bias2
__global__ void k4_gather_l2(const int* __restrict__ rowstart,
                             const int* __restrict__ deg,
                             const int* __restrict__ csr,
                             const float* __restrict__ h2,
                             const float* __restrict__ as2,
                             const float* __restrict__ ad2,
                             const float* __restrict__ bias2,
                             float* __restrict__ out, int N)
{
    int t = threadIdx.x;
    int node = blockIdx.x * 32 + (t >> 3);
    int d = t & 7;
    if (node >= N) return;
    float adi = ad2[node];
    float ex = __expf(leaky(as2[node] + adi));    // self-loop
    float den = ex;
    float num = ex * h2[(size_t)node * 8 + d];
    int base = rowstart[node], cnt = deg[node];
    for (int k = 0; k < cnt; ++k) {
        int j = csr[base + k];
        float e2 = __expf(leaky(as2[j] + adi));
        den += e2;
        num += e2 * h2[(size_t)j * 8 + d];
    }
    out[(size_t)node * 8 + d] = num / (den + 1e-16f) + bias2[d];
}

// ---------- launch ----------

extern "C" void kernel_launch(void* const* d_in, const int* in_sizes, int n_in,
                              void* d_out, int out_size, void* d_ws, size_t ws_size,
                              hipStream_t stream) {
    const float* x    = (const float*)d_in[0];
    const int*   ei   = (const int*)d_in[1];
    const float* W1   = (const float*)d_in[2];
    const float* asw1 = (const float*)d_in[3];
    const float* adw1 = (const float*)d_in[4];
    const float* b1   = (const float*)d_in[5];
    const float* W2   = (const float*)d_in[6];
    const float* asw2 = (const float*)d_in[7];
    const float* adw2 = (const float*)d_in[8];
    const float* b2   = (const float*)d_in[9];
    float* out = (float*)d_out;

    int N = in_sizes[0] / F_IN;
    int E = in_sizes[1] / 2;
    int nblk = (N + 1023) / 1024;

    // workspace layout (floats first, then ints; all 16B-aligned sizes)
    float* fw   = (float*)d_ws;
    float* h1   = fw;                          // N*64
    float* hl2  = h1  + (size_t)N * 64;        // N*64
    float* as1  = hl2 + (size_t)N * 64;        // N*8
    float* ad1  = as1 + (size_t)N * 8;         // N*8
    float* h2   = ad1 + (size_t)N * 8;         // N*8
    float* as2  = h2  + (size_t)N * 8;         // N
    float* ad2  = as2 + (size_t)N;             // N
    int* iw       = (int*)(ad2 + (size_t)N);
    int* deg      = iw;                        // N
    int* partial  = deg + N;                   // N
    int* rowstart = partial + N;               // N
    int* cursor   = rowstart + N;              // N
    int* blocksum = cursor + N;                // nblk (<=4096)
    int* csr      = blocksum + 4096;           // E

    // CSR build
    zero_int<<<256, 256, 0, stream>>>(deg, N);
    count_deg<<<(E + 255) / 256, 256, 0, stream>>>(ei, E, deg);
    scan1<<<nblk, 256, 0, stream>>>(deg, partial, blocksum, N);
    scan2<<<1, 256, 0, stream>>>(blocksum, nblk);
    scan3<<<(N + 255) / 256, 256, 0, stream>>>(partial, blocksum, rowstart, cursor, N);
    scatter_csr<<<(E + 255) / 256, 256, 0, stream>>>(ei, E, cursor, csr);

    // Layer 1
    k1_node_l1<<<(N + 3) / 4, 256, 0, stream>>>(x, W1, asw1, adw1, h1, as1, ad1, N);
    k2_gather_l1<<<(N + 31) / 32, 256, 0, stream>>>(rowstart, deg, csr, h1, as1, ad1, b1, hl2, N);

    // Layer 2
    k3_node_l2<<<(N + 31) / 32, 256, 0, stream>>>(hl2, W2, asw2, adw2, h2, as2, ad2, N);
    k4_gather_l2<<<(N + 31) / 32, 256, 0, stream>>>(rowstart, deg, csr, h2, as2, ad2, b2, out, N);
}